// Round 1
// baseline (289.738 us; speedup 1.0000x reference)
//
#include <hip/hip_runtime.h>
#include <stdint.h>

// Equivariance: NCONF=8192, NT=64, NX=64
// out0[i,t,j] = sum_x phi[i,t,(x'-T0)%64] * W[x',(j+T0)%64] + b[(j+T0)%64]
// out1[i]     = 64 * log|det W|
// T0[i] = min-rule over argmin_t |phi[i,t,0]| and argmin_t |phi[i,t,1]|

typedef _Float16 half2v __attribute__((ext_vector_type(2)));
typedef _Float16 half8v __attribute__((ext_vector_type(8)));
typedef float float4v __attribute__((ext_vector_type(4)));

#if defined(__has_builtin)
#if __has_builtin(__builtin_amdgcn_fdot2)
#define HAVE_FDOT2 1
#endif
#endif

__device__ __forceinline__ float dot2f(half2v a, half2v b, float c) {
#ifdef HAVE_FDOT2
  return __builtin_amdgcn_fdot2(a, b, c, false);
#else
  return c + (float)a.x * (float)b.x + (float)a.y * (float)b.y;
#endif
}

union H8 {
  half8v v;
  half2v p[4];
};

__global__ __launch_bounds__(64) void equiv_kernel(
    const float* __restrict__ phi, const float* __restrict__ W,
    const float* __restrict__ b, float* __restrict__ out) {
  // 16 KB shared: matmul blocks use 2x f16 4096-elem tiles; block 0 uses f32 64x64 for LU
  __shared__ float smemF[4096];
  _Float16* sPhi = (_Float16*)smemF;         // [64][64] f16, chunk-swizzled
  _Float16* sW = ((_Float16*)smemF) + 4096;  // [64][64] f16: sW[j][x'] = W[x'][(j+T0)&63]
  const int lane = threadIdx.x;

  if (blockIdx.x == 0) {
    // ---- LU with partial pivoting on W (64x64, stride 64) -> logabsdet ----
    float* A = smemF;
    for (int r = 0; r < 64; ++r) A[r * 64 + lane] = W[r * 64 + lane];
    __syncthreads();
    float ldsum = 0.f;
    for (int k = 0; k < 64; ++k) {
      __syncthreads();
      // pivot search: max |A[t][k]| over t >= k (64-way bank conflict, but tiny)
      unsigned long long key = 0ull;
      if (lane >= k) {
        float v = fabsf(A[lane * 64 + k]);
        key = (((unsigned long long)__float_as_uint(v)) << 6) | (unsigned long long)lane;
      }
#pragma unroll
      for (int m = 1; m < 64; m <<= 1) {
        unsigned long long o = __shfl_xor(key, m);
        key = (o > key) ? o : key;
      }
      int p = (int)(key & 63ull);
      if (p != k) {
        float tk = A[k * 64 + lane], tp = A[p * 64 + lane];
        A[k * 64 + lane] = tp;
        A[p * 64 + lane] = tk;
      }
      __syncthreads();
      float akk = A[k * 64 + k];
      ldsum += logf(fabsf(akk));
      float rk = 1.0f / akk;
      float pivrow = A[k * 64 + lane];  // this lane's column of the pivot row
      for (int t = k + 1; t < 64; ++t) {
        float m = A[t * 64 + k] * rk;  // broadcast read (col k untouched this iter)
        if (lane > k) A[t * 64 + lane] -= m * pivrow;
      }
    }
    float ld = 64.0f * ldsum;  // NT * logabsdet
    float* outLD = out + (size_t)8192 * 4096;
    for (int it = 0; it < 128; ++it) outLD[it * 64 + lane] = ld;
    return;
  }

  const int cfg = (int)blockIdx.x - 1;
  const float4v* phiv = (const float4v*)(phi + (size_t)cfg * 4096);
  const float4v* Wv = (const float4v*)W;

  // ---- coalesced loads: phi tile (16 KB) and W (16 KB) into registers ----
  float4v pv[16], wv[16];
#pragma unroll
  for (int it = 0; it < 16; ++it) pv[it] = phiv[it * 64 + lane];
#pragma unroll
  for (int it = 0; it < 16; ++it) wv[it] = Wv[it * 64 + lane];

  // ---- T0: argmin_t |phi[t][0]|, |phi[t][1]| from loaded regs ----
  // float4 #f holds row t=f>>4, cols (f&15)*4..+3; cols 0,1 live in lanes with (lane&15)==0
  unsigned long long k0 = ~0ull, k1 = ~0ull;
  if ((lane & 15) == 0) {
#pragma unroll
    for (int it = 0; it < 16; ++it) {
      int t = it * 4 + (lane >> 4);
      unsigned long long c0 =
          (((unsigned long long)__float_as_uint(fabsf(pv[it].x))) << 6) | (unsigned long long)t;
      unsigned long long c1 =
          (((unsigned long long)__float_as_uint(fabsf(pv[it].y))) << 6) | (unsigned long long)t;
      k0 = c0 < k0 ? c0 : k0;
      k1 = c1 < k1 ? c1 : k1;
    }
  }
#pragma unroll
  for (int m = 1; m < 64; m <<= 1) {
    unsigned long long o0 = __shfl_xor(k0, m);
    unsigned long long o1 = __shfl_xor(k1, m);
    k0 = o0 < k0 ? o0 : k0;
    k1 = o1 < k1 ? o1 : k1;
  }
  int t0i = (int)(k0 & 63ull), t1i = (int)(k1 & 63ull);
  int T0 = (t0i > t1i) ? t1i : t0i;

  // ---- stage phi rolled into LDS: sPhi[t][x'] = phi[t][(x'-T0)&63] ----
  // element (t, xg) lands at x' = (xg+T0)&63; XOR chunk swizzle by (t>>3) for
  // conflict-free ds_read_b128 in the inner loop.
#pragma unroll
  for (int it = 0; it < 16; ++it) {
    int flat4 = it * 64 + lane;
    int t = flat4 >> 4;
    int xg = (flat4 & 15) << 2;
    int tsw = t >> 3;
#pragma unroll
    for (int kk = 0; kk < 4; ++kk) {
      int xp = (xg + kk + T0) & 63;
      int pos = t * 64 + ((((xp >> 3) ^ tsw) << 3) | (xp & 7));
      sPhi[pos] = (_Float16)pv[it][kk];
    }
  }
  // ---- stage W transposed+rolled: sW[j][x'] = W[x'][(j+T0)&63] (j=(c-T0)&63) ----
#pragma unroll
  for (int it = 0; it < 16; ++it) {
    int flat4 = it * 64 + lane;
    int xp = flat4 >> 4;
    int cg = (flat4 & 15) << 2;
#pragma unroll
    for (int kk = 0; kk < 4; ++kk) {
      int j = (cg + kk + 64 - T0) & 63;
      int pos = j * 64 + ((((xp >> 3) ^ (j >> 3)) << 3) | (xp & 7));
      sW[pos] = (_Float16)wv[it][kk];
    }
  }
  __syncthreads();

  // ---- 8x8 register tile per lane, f16 dot2 inner loop ----
  const int ty = lane >> 3, tx = lane & 7;
  const int t0 = ty << 3, j0 = tx << 3;
  float acc[8][8];
#pragma unroll
  for (int r = 0; r < 8; ++r)
#pragma unroll
    for (int c = 0; c < 8; ++c) acc[r][c] = 0.f;

  for (int xb = 0; xb < 8; ++xb) {
    H8 a[8];
#pragma unroll
    for (int r = 0; r < 8; ++r)
      a[r].v = *(const half8v*)&sPhi[(t0 + r) * 64 + ((xb ^ ty) << 3)];
#pragma unroll
    for (int c = 0; c < 8; ++c) {
      H8 bb;
      bb.v = *(const half8v*)&sW[(j0 + c) * 64 + ((xb ^ tx) << 3)];
#pragma unroll
      for (int r = 0; r < 8; ++r) {
        float av = acc[r][c];
#pragma unroll
        for (int p = 0; p < 4; ++p) av = dot2f(a[r].p[p], bb.p[p], av);
        acc[r][c] = av;
      }
    }
  }

  // ---- epilogue: add rolled bias, coalesced float4 stores ----
  float bv[8];
#pragma unroll
  for (int c = 0; c < 8; ++c) bv[c] = b[(j0 + c + T0) & 63];
  float* outp = out + (size_t)cfg * 4096;
#pragma unroll
  for (int r = 0; r < 8; ++r) {
#pragma unroll
    for (int cq = 0; cq < 2; ++cq) {
      float4v o;
#pragma unroll
      for (int kk = 0; kk < 4; ++kk) o[kk] = acc[r][cq * 4 + kk] + bv[cq * 4 + kk];
      *(float4v*)&outp[(t0 + r) * 64 + j0 + (cq << 2)] = o;
    }
  }
}

extern "C" void kernel_launch(void* const* d_in, const int* in_sizes, int n_in,
                              void* d_out, int out_size, void* d_ws, size_t ws_size,
                              hipStream_t stream) {
  const float* phi = (const float*)d_in[0];
  const float* W = (const float*)d_in[1];
  const float* b = (const float*)d_in[2];
  float* out = (float*)d_out;
  // block 0: LU/logdet (dispatched first, hides under the 8192 matmul blocks)
  equiv_kernel<<<dim3(8193), dim3(64), 0, stream>>>(phi, W, b, out);
}

// Round 2
// 286.293 us; speedup vs baseline: 1.0120x; 1.0120x over previous
//
#include <hip/hip_runtime.h>
#include <stdint.h>

// Equivariance: NCONF=8192, NT=64, NX=64
// out0[i,t,j] = sum_y phi[i,t,y] * W[(y+T0)&63, (j+T0)&63] + b[(j+T0)&63]
// out1[i]     = 64 * log|det W|
// T0[i] = min-rule over argmin_t |phi[i,t,0]| and argmin_t |phi[i,t,1]|
//
// Roll identity: out = roll_back(NN(roll_fwd(phi))) with linear NN collapses to
// phi (unrolled) times a doubly-rolled W. The 64 possible rolled+transposed W
// variants (512 KB f16) are precomputed once into d_ws -> per-config W staging
// and all roll address math vanish from the hot loop.

typedef _Float16 half2v __attribute__((ext_vector_type(2)));
typedef _Float16 half4v __attribute__((ext_vector_type(4)));
typedef _Float16 half8v __attribute__((ext_vector_type(8)));
typedef float float4v __attribute__((ext_vector_type(4)));

#if defined(__has_builtin)
#if __has_builtin(__builtin_amdgcn_fdot2)
#define HAVE_FDOT2 1
#endif
#endif

__device__ __forceinline__ float dot2f(half2v a, half2v b, float c) {
#ifdef HAVE_FDOT2
  return __builtin_amdgcn_fdot2(a, b, c, false);
#else
  return c + (float)a.x * (float)b.x + (float)a.y * (float)b.y;
#endif
}

union H8 {
  half8v v;
  half2v p[4];
};

// ---- prep: WT2[s][j][y] = (f16) W[(y+s)&63][(j+s)&63]  (transposed: y contiguous)
__global__ __launch_bounds__(256) void wt2_prep(const float* __restrict__ W,
                                                _Float16* __restrict__ wt2) {
  const int s = blockIdx.x;
  const int tid = threadIdx.x;
#pragma unroll
  for (int it = 0; it < 16; ++it) {
    int flat = it * 256 + tid;
    int j = flat >> 6;
    int y = flat & 63;
    float v = W[((y + s) & 63) * 64 + ((j + s) & 63)];
    wt2[(size_t)s * 4096 + flat] = (_Float16)v;
  }
}

__global__ __launch_bounds__(256) void equiv_main(
    const float* __restrict__ phi, const float* __restrict__ W,
    const float* __restrict__ b, const _Float16* __restrict__ wt2,
    float* __restrict__ out) {
  __shared__ __align__(16) unsigned char smem[32768];
  const int lane = threadIdx.x & 63;

  if (blockIdx.x == 0) {
    // ---- LU with partial pivoting, lane t owns row t, padded stride 65 ----
    if (threadIdx.x >= 64) return;  // single wave, no barriers needed
    float* A = (float*)smem;        // [64][65] = 16.6 KB
    const int t = lane;
    for (int r = 0; r < 64; ++r) A[r * 65 + lane] = W[r * 64 + lane];
    float ldsum = 0.f;
    for (int k = 0; k < 64; ++k) {
      float av = (t >= k) ? fabsf(A[t * 65 + k]) : -1.0f;
      unsigned long long key =
          (((unsigned long long)__float_as_uint(av < 0.f ? 0.f : av)) << 6) |
          (unsigned long long)t;
      if (t < k) key = 0ull;
#pragma unroll
      for (int m = 1; m < 64; m <<= 1) {
        unsigned long long o = __shfl_xor(key, m);
        key = (o > key) ? o : key;
      }
      int p = (int)(key & 63ull);
      if (p != k) {  // wave-uniform; lane acts as column index, conflict-free
        float vk = A[k * 65 + lane];
        float vp = A[p * 65 + lane];
        A[k * 65 + lane] = vp;
        A[p * 65 + lane] = vk;
      }
      float piv = A[k * 65 + k];  // broadcast
      ldsum += logf(fabsf(piv));
      float rk = 1.0f / piv;
      float m = (t > k) ? A[t * 65 + k] * rk : 0.f;
      for (int c = k + 1; c < 64; ++c) {
        float pr = A[k * 65 + c];  // broadcast
        if (t > k) A[t * 65 + c] -= m * pr;
      }
    }
    float ld = 64.0f * ldsum;  // NT * logabsdet (uniform across lanes)
    float* outLD = out + (size_t)8192 * 4096;
    for (int it = 0; it < 128; ++it) outLD[it * 64 + lane] = ld;
    return;
  }

  const int wave = threadIdx.x >> 6;
  const int cfg = ((int)blockIdx.x - 1) * 4 + wave;
  _Float16* sPhi = ((_Float16*)smem) + wave * 4096;  // wave-private 8 KB

  // ---- coalesced phi load (16 x float4 per lane = full 16 KB tile) ----
  const float4v* phiv = (const float4v*)(phi + (size_t)cfg * 4096);
  float4v pv[16];
#pragma unroll
  for (int it = 0; it < 16; ++it) pv[it] = phiv[it * 64 + lane];

  // ---- T0 from registers: argmin_t |phi[t][0]|, |phi[t][1]| ----
  unsigned long long k0 = ~0ull, k1 = ~0ull;
  if ((lane & 15) == 0) {
#pragma unroll
    for (int it = 0; it < 16; ++it) {
      int tt = it * 4 + (lane >> 4);
      unsigned long long c0 =
          (((unsigned long long)__float_as_uint(fabsf(pv[it].x))) << 6) | (unsigned long long)tt;
      unsigned long long c1 =
          (((unsigned long long)__float_as_uint(fabsf(pv[it].y))) << 6) | (unsigned long long)tt;
      k0 = c0 < k0 ? c0 : k0;
      k1 = c1 < k1 ? c1 : k1;
    }
  }
#pragma unroll
  for (int m = 1; m < 64; m <<= 1) {
    unsigned long long o0 = __shfl_xor(k0, m);
    unsigned long long o1 = __shfl_xor(k1, m);
    k0 = o0 < k0 ? o0 : k0;
    k1 = o1 < k1 ? o1 : k1;
  }
  int t0i = (int)(k0 & 63ull), t1i = (int)(k1 & 63ull);
  const int T0 = (t0i > t1i) ? t1i : t0i;

  // ---- stage phi UNROLLED to f16 LDS, XOR-chunk swizzle by (t>>3) ----
#pragma unroll
  for (int it = 0; it < 16; ++it) {
    int flat4 = it * 64 + lane;
    int t = flat4 >> 4;
    int y0 = (flat4 & 15) << 2;
    int ch = (y0 >> 3) ^ (t >> 3);
    int off = y0 & 7;  // 0 or 4
    half4v h;
    h.x = (_Float16)pv[it].x;
    h.y = (_Float16)pv[it].y;
    h.z = (_Float16)pv[it].z;
    h.w = (_Float16)pv[it].w;
    *(half4v*)&sPhi[t * 64 + (ch << 3) + off] = h;
  }
  // wave-private LDS: compiler's lgkmcnt tracking suffices, no barrier.

  // ---- 8x8 register tile; W fragments streamed from L2-resident WT2[T0] ----
  const int ty = lane >> 3, tx = lane & 7;
  const int t0 = ty << 3, j0 = tx << 3;
  const _Float16* wt = wt2 + (size_t)T0 * 4096;
  float acc[8][8];
#pragma unroll
  for (int r = 0; r < 8; ++r)
#pragma unroll
    for (int c = 0; c < 8; ++c) acc[r][c] = 0.f;

  for (int xb = 0; xb < 8; ++xb) {
    H8 a[8];
#pragma unroll
    for (int r = 0; r < 8; ++r)
      a[r].v = *(const half8v*)&sPhi[(t0 + r) * 64 + ((xb ^ ty) << 3)];
#pragma unroll
    for (int c = 0; c < 8; ++c) {
      H8 bb;
      bb.v = *(const half8v*)&wt[(j0 + c) * 64 + (xb << 3)];
#pragma unroll
      for (int r = 0; r < 8; ++r) {
        float av = acc[r][c];
#pragma unroll
        for (int p = 0; p < 4; ++p) av = dot2f(a[r].p[p], bb.p[p], av);
        acc[r][c] = av;
      }
    }
  }

  // ---- epilogue: rolled bias + coalesced float4 stores ----
  float bv[8];
#pragma unroll
  for (int c = 0; c < 8; ++c) bv[c] = b[(j0 + c + T0) & 63];
  float* outp = out + (size_t)cfg * 4096;
#pragma unroll
  for (int r = 0; r < 8; ++r) {
#pragma unroll
    for (int cq = 0; cq < 2; ++cq) {
      float4v o;
#pragma unroll
      for (int kk = 0; kk < 4; ++kk) o[kk] = acc[r][cq * 4 + kk] + bv[cq * 4 + kk];
      *(float4v*)&outp[(t0 + r) * 64 + j0 + (cq << 2)] = o;
    }
  }
}

extern "C" void kernel_launch(void* const* d_in, const int* in_sizes, int n_in,
                              void* d_out, int out_size, void* d_ws, size_t ws_size,
                              hipStream_t stream) {
  const float* phi = (const float*)d_in[0];
  const float* W = (const float*)d_in[1];
  const float* b = (const float*)d_in[2];
  float* out = (float*)d_out;
  _Float16* wt2 = (_Float16*)d_ws;  // 64 shifts x 64x64 f16 = 512 KB

  wt2_prep<<<dim3(64), dim3(256), 0, stream>>>(W, wt2);
  // block 0 = LU/logdet (overlaps with the 2048 GEMM blocks)
  equiv_main<<<dim3(2049), dim3(256), 0, stream>>>(phi, W, b, wt2, out);
}

// Round 3
// 282.021 us; speedup vs baseline: 1.0274x; 1.0151x over previous
//
#include <hip/hip_runtime.h>
#include <stdint.h>

// Equivariance: NCONF=8192, NT=64, NX=64
// out0[i,t,j] = sum_y phi[i,t,y] * W[(y+T0)&63, (j+T0)&63] + b[(j+T0)&63]
// out1[i]     = 64 * log|det W|
// T0[i] = min-rule over argmin_t |phi[i,t,0]| and argmin_t |phi[i,t,1]|
//
// R3: zero-LDS MFMA formulation. 1 wave = 1 config. phi loaded directly in
// MFMA A-operand layout (m=lane&15, k=quad*8+j) as fp32 dwordx4 pairs, f16
// convert in-register; argmin computed from the fp32 quad-0 fragments before
// conversion (bit-exact tie-break vs reference). B = WT2[T0] (precomputed,
// L2-resident, 8x16B loads/wave). 32 MFMAs accumulate the 64x64 output.

typedef _Float16 half8v __attribute__((ext_vector_type(8)));
typedef float float4v __attribute__((ext_vector_type(4)));

__global__ __launch_bounds__(256) void wt2_prep(const float* __restrict__ W,
                                                _Float16* __restrict__ wt2) {
  // WT2[s][j][y] = (f16) W[(y+s)&63][(j+s)&63]   (y contiguous)
  const int s = blockIdx.x;
  const int tid = threadIdx.x;
#pragma unroll
  for (int it = 0; it < 16; ++it) {
    int flat = it * 256 + tid;
    int j = flat >> 6;
    int y = flat & 63;
    wt2[(size_t)s * 4096 + flat] = (_Float16)W[((y + s) & 63) * 64 + ((j + s) & 63)];
  }
}

__global__ __launch_bounds__(256) void equiv_main(
    const float* __restrict__ phi, const float* __restrict__ W,
    const float* __restrict__ b, const _Float16* __restrict__ wt2,
    float* __restrict__ out) {
  const int lane = threadIdx.x & 63;

  if (blockIdx.x == 0) {
    // ---- LU with partial pivoting (single wave), padded stride 65 ----
    if (threadIdx.x >= 64) return;
    __shared__ float A[64 * 65];
    const int t = lane;
    for (int r = 0; r < 64; ++r) A[r * 65 + lane] = W[r * 64 + lane];
    float ldsum = 0.f;
    for (int k = 0; k < 64; ++k) {
      float av = (t >= k) ? fabsf(A[t * 65 + k]) : -1.0f;
      unsigned long long key =
          (((unsigned long long)__float_as_uint(av < 0.f ? 0.f : av)) << 6) |
          (unsigned long long)t;
      if (t < k) key = 0ull;
#pragma unroll
      for (int m = 1; m < 64; m <<= 1) {
        unsigned long long o = __shfl_xor(key, m);
        key = (o > key) ? o : key;
      }
      int p = (int)(key & 63ull);
      if (p != k) {
        float vk = A[k * 65 + lane], vp = A[p * 65 + lane];
        A[k * 65 + lane] = vp;
        A[p * 65 + lane] = vk;
      }
      float piv = A[k * 65 + k];
      ldsum += logf(fabsf(piv));
      float rk = 1.0f / piv;
      float m = (t > k) ? A[t * 65 + k] * rk : 0.f;
      for (int c = k + 1; c < 64; ++c) {
        float pr = A[k * 65 + c];
        if (t > k) A[t * 65 + c] -= m * pr;
      }
    }
    float ld = 64.0f * ldsum;  // NT * logabsdet
    float* outLD = out + (size_t)8192 * 4096;
    for (int it = 0; it < 128; ++it) outLD[it * 64 + lane] = ld;
    return;
  }

  const int wave = threadIdx.x >> 6;
  const int cfg = ((int)blockIdx.x - 1) * 4 + wave;
  const float* ph = phi + (size_t)cfg * 4096;
  const int m = lane & 15;   // MFMA row/col within tile
  const int q = lane >> 4;   // quad: k-chunk selector

  // ---- load full phi tile in MFMA A-layout: frag(mt,ks) covers rows
  // mt*16+m, cols ks*32 + q*8 .. +7, as two fp32 dwordx4 ----
  float4v f[4][2][2];
#pragma unroll
  for (int mt = 0; mt < 4; ++mt)
#pragma unroll
    for (int ks = 0; ks < 2; ++ks)
#pragma unroll
      for (int h = 0; h < 2; ++h)
        f[mt][ks][h] = *(const float4v*)&ph[(mt * 16 + m) * 64 + ks * 32 + q * 8 + h * 4];

  // ---- T0 argmin from fp32 regs: cols 0,1 live in quad-0 fragments ----
  unsigned long long k0 = ~0ull, k1 = ~0ull;
  if (q == 0) {
#pragma unroll
    for (int mt = 0; mt < 4; ++mt) {
      unsigned long long t = (unsigned long long)(mt * 16 + m);
      unsigned long long c0 =
          (((unsigned long long)__float_as_uint(fabsf(f[mt][0][0].x))) << 6) | t;
      unsigned long long c1 =
          (((unsigned long long)__float_as_uint(fabsf(f[mt][0][0].y))) << 6) | t;
      k0 = c0 < k0 ? c0 : k0;
      k1 = c1 < k1 ? c1 : k1;
    }
  }
#pragma unroll
  for (int s = 1; s < 64; s <<= 1) {
    unsigned long long o0 = __shfl_xor(k0, s);
    unsigned long long o1 = __shfl_xor(k1, s);
    k0 = o0 < k0 ? o0 : k0;
    k1 = o1 < k1 ? o1 : k1;
  }
  int t0i = (int)(k0 & 63ull), t1i = (int)(k1 & 63ull);
  const int T0 = (t0i > t1i) ? t1i : t0i;

  // ---- B fragments from L2-resident WT2[T0]: lane holds B[k][n], n=m,
  // k = ks*32 + q*8 + j  -> wt2 offset (nt*16+m)*64 + ks*32 + q*8 ----
  const _Float16* wt = wt2 + (size_t)T0 * 4096;
  half8v Bf[2][4];
#pragma unroll
  for (int ks = 0; ks < 2; ++ks)
#pragma unroll
    for (int nt = 0; nt < 4; ++nt)
      Bf[ks][nt] = *(const half8v*)&wt[(nt * 16 + m) * 64 + ks * 32 + q * 8];

  // ---- convert A fragments to f16 ----
  half8v Af[4][2];
#pragma unroll
  for (int mt = 0; mt < 4; ++mt)
#pragma unroll
    for (int ks = 0; ks < 2; ++ks) {
      half8v h;
#pragma unroll
      for (int kk = 0; kk < 4; ++kk) {
        h[kk] = (_Float16)f[mt][ks][0][kk];
        h[kk + 4] = (_Float16)f[mt][ks][1][kk];
      }
      Af[mt][ks] = h;
    }

  // ---- 32 MFMAs: acc[mt][nt] over 2 k-steps ----
  float4v acc[4][4];
#pragma unroll
  for (int mt = 0; mt < 4; ++mt)
#pragma unroll
    for (int nt = 0; nt < 4; ++nt) acc[mt][nt] = (float4v)(0.f);
#pragma unroll
  for (int ks = 0; ks < 2; ++ks)
#pragma unroll
    for (int mt = 0; mt < 4; ++mt)
#pragma unroll
      for (int nt = 0; nt < 4; ++nt)
        acc[mt][nt] = __builtin_amdgcn_mfma_f32_16x16x32_f16(Af[mt][ks], Bf[ks][nt],
                                                             acc[mt][nt], 0, 0, 0);

  // ---- epilogue: rolled bias + stores (C layout: col=lane&15, row=q*4+r) ----
  float bias[4];
#pragma unroll
  for (int nt = 0; nt < 4; ++nt) bias[nt] = b[(nt * 16 + m + T0) & 63];
  float* op = out + (size_t)cfg * 4096;
#pragma unroll
  for (int mt = 0; mt < 4; ++mt)
#pragma unroll
    for (int nt = 0; nt < 4; ++nt)
#pragma unroll
      for (int r = 0; r < 4; ++r)
        op[(mt * 16 + q * 4 + r) * 64 + nt * 16 + m] = acc[mt][nt][r] + bias[nt];
}

extern "C" void kernel_launch(void* const* d_in, const int* in_sizes, int n_in,
                              void* d_out, int out_size, void* d_ws, size_t ws_size,
                              hipStream_t stream) {
  const float* phi = (const float*)d_in[0];
  const float* W = (const float*)d_in[1];
  const float* b = (const float*)d_in[2];
  float* out = (float*)d_out;
  _Float16* wt2 = (_Float16*)d_ws;  // 64 shifts x 64x64 f16 = 512 KB

  wt2_prep<<<dim3(64), dim3(256), 0, stream>>>(W, wt2);
  equiv_main<<<dim3(2049), dim3(256), 0, stream>>>(phi, W, b, wt2, out);
}

// Round 4
// 241.267 us; speedup vs baseline: 1.2009x; 1.1689x over previous
//
#include <hip/hip_runtime.h>
#include <stdint.h>

// Equivariance: NCONF=8192, NT=64, NX=64
// out0[i,t,j] = sum_y phi[i,t,y] * W[(y+T0)&63, (j+T0)&63] + b[(j+T0)&63]
// out1[i]     = 64 * log|det W|
// T0[i] = min-rule over argmin_t |phi[i,t,0]| and argmin_t |phi[i,t,1]|
//
// R4: the LU/logdet block was the bottleneck (serial LDS RMW chain ~130us on
// one wave while the 8192 GEMM waves finished in ~40us). LU is now fully
// register-resident: lane t owns row t; after each elimination the row shifts
// down one register so the active pivot column is always r[0] -> no dynamic
// register indexing, no LDS, ~130 instrs/step * 64 steps ~= 10-15us, hidden
// under the GEMM blocks. GEMM path: zero-LDS MFMA, 1 wave = 1 config,
// B = precomputed doubly-rolled W table (L2-resident, 8x16B loads/wave).

typedef _Float16 half8v __attribute__((ext_vector_type(8)));
typedef float float4v __attribute__((ext_vector_type(4)));

__global__ __launch_bounds__(256) void wt2_prep(const float* __restrict__ W,
                                                _Float16* __restrict__ wt2) {
  // WT2[s][j][y] = (f16) W[(y+s)&63][(j+s)&63]   (y contiguous)
  const int s = blockIdx.x;
  const int tid = threadIdx.x;
#pragma unroll
  for (int it = 0; it < 16; ++it) {
    int flat = it * 256 + tid;
    int j = flat >> 6;
    int y = flat & 63;
    wt2[(size_t)s * 4096 + flat] = (_Float16)W[((y + s) & 63) * 64 + ((j + s) & 63)];
  }
}

__global__ __launch_bounds__(256) void equiv_main(
    const float* __restrict__ phi, const float* __restrict__ W,
    const float* __restrict__ b, const _Float16* __restrict__ wt2,
    float* __restrict__ out) {
  const int lane = threadIdx.x & 63;

  if (blockIdx.x == 0) {
    // ---- register-resident LU with partial pivoting (no swaps: used-mask) ---
    if (threadIdx.x >= 64) return;  // single wave
    const int t = lane;
    float r[64];  // r[i] = A[t][k+i] at step k (shift-down keeps pivot col at r[0])
#pragma unroll
    for (int i = 0; i < 64; ++i) r[i] = W[t * 64 + i];
    bool used = false;
    float ldsum = 0.f;
    for (int k = 0; k < 64; ++k) {
      float v = r[0];
      float av = used ? 0.f : fabsf(v);
      // masked butterfly argmax over lanes: key = (bits|av|)<<6 | t
      unsigned long long key = used
          ? 0ull
          : ((((unsigned long long)__float_as_uint(av)) << 6) | (unsigned long long)t);
#pragma unroll
      for (int s = 1; s < 64; s <<= 1) {
        unsigned long long o = __shfl_xor(key, s);
        key = (o > key) ? o : key;
      }
      int p = (int)(key & 63ull);
      float piv = __shfl(v, p);
      ldsum += logf(fabsf(piv));
      if (t == p) used = true;
      float m = used ? 0.f : (v / piv);  // used rows (incl. new pivot) only shift
      // fused update + shift-down: r[i-1] = r[i] - m * prow[i]
#pragma unroll
      for (int i = 1; i < 64; ++i) {
        float pe = __shfl(r[i], p);
        r[i - 1] = r[i] - m * pe;
      }
      r[63] = 0.f;
    }
    float ld = 64.0f * ldsum;  // NT * logabsdet (uniform across lanes)
    float* outLD = out + (size_t)8192 * 4096;
    for (int it = 0; it < 128; ++it) outLD[it * 64 + lane] = ld;
    return;
  }

  const int wave = threadIdx.x >> 6;
  const int cfg = ((int)blockIdx.x - 1) * 4 + wave;
  const float* ph = phi + (size_t)cfg * 4096;
  const int m = lane & 15;  // MFMA row/col within tile
  const int q = lane >> 4;  // quad: k-chunk selector

  // ---- load full phi tile in MFMA A-layout: frag(mt,ks) covers rows
  // mt*16+m, cols ks*32 + q*8 .. +7, as two fp32 dwordx4 ----
  float4v f[4][2][2];
#pragma unroll
  for (int mt = 0; mt < 4; ++mt)
#pragma unroll
    for (int ks = 0; ks < 2; ++ks)
#pragma unroll
      for (int h = 0; h < 2; ++h)
        f[mt][ks][h] = *(const float4v*)&ph[(mt * 16 + m) * 64 + ks * 32 + q * 8 + h * 4];

  // ---- T0 argmin from fp32 regs: cols 0,1 live in quad-0 fragments ----
  unsigned long long k0 = ~0ull, k1 = ~0ull;
  if (q == 0) {
#pragma unroll
    for (int mt = 0; mt < 4; ++mt) {
      unsigned long long tt = (unsigned long long)(mt * 16 + m);
      unsigned long long c0 =
          (((unsigned long long)__float_as_uint(fabsf(f[mt][0][0].x))) << 6) | tt;
      unsigned long long c1 =
          (((unsigned long long)__float_as_uint(fabsf(f[mt][0][0].y))) << 6) | tt;
      k0 = c0 < k0 ? c0 : k0;
      k1 = c1 < k1 ? c1 : k1;
    }
  }
#pragma unroll
  for (int s = 1; s < 64; s <<= 1) {
    unsigned long long o0 = __shfl_xor(k0, s);
    unsigned long long o1 = __shfl_xor(k1, s);
    k0 = o0 < k0 ? o0 : k0;
    k1 = o1 < k1 ? o1 : k1;
  }
  int t0i = (int)(k0 & 63ull), t1i = (int)(k1 & 63ull);
  const int T0 = (t0i > t1i) ? t1i : t0i;

  // ---- B fragments from L2-resident WT2[T0] ----
  const _Float16* wt = wt2 + (size_t)T0 * 4096;
  half8v Bf[2][4];
#pragma unroll
  for (int ks = 0; ks < 2; ++ks)
#pragma unroll
    for (int nt = 0; nt < 4; ++nt)
      Bf[ks][nt] = *(const half8v*)&wt[(nt * 16 + m) * 64 + ks * 32 + q * 8];

  // ---- convert A fragments to f16 ----
  half8v Af[4][2];
#pragma unroll
  for (int mt = 0; mt < 4; ++mt)
#pragma unroll
    for (int ks = 0; ks < 2; ++ks) {
      half8v h;
#pragma unroll
      for (int kk = 0; kk < 4; ++kk) {
        h[kk] = (_Float16)f[mt][ks][0][kk];
        h[kk + 4] = (_Float16)f[mt][ks][1][kk];
      }
      Af[mt][ks] = h;
    }

  // ---- 32 MFMAs: acc[mt][nt] over 2 k-steps ----
  float4v acc[4][4];
#pragma unroll
  for (int mt = 0; mt < 4; ++mt)
#pragma unroll
    for (int nt = 0; nt < 4; ++nt) acc[mt][nt] = (float4v)(0.f);
#pragma unroll
  for (int ks = 0; ks < 2; ++ks)
#pragma unroll
    for (int mt = 0; mt < 4; ++mt)
#pragma unroll
      for (int nt = 0; nt < 4; ++nt)
        acc[mt][nt] = __builtin_amdgcn_mfma_f32_16x16x32_f16(Af[mt][ks], Bf[ks][nt],
                                                             acc[mt][nt], 0, 0, 0);

  // ---- epilogue: rolled bias + stores (C layout: col=lane&15, row=q*4+r) ----
  float bias[4];
#pragma unroll
  for (int nt = 0; nt < 4; ++nt) bias[nt] = b[(nt * 16 + m + T0) & 63];
  float* op = out + (size_t)cfg * 4096;
#pragma unroll
  for (int mt = 0; mt < 4; ++mt)
#pragma unroll
    for (int nt = 0; nt < 4; ++nt)
#pragma unroll
      for (int r = 0; r < 4; ++r)
        op[(mt * 16 + q * 4 + r) * 64 + nt * 16 + m] = acc[mt][nt][r] + bias[nt];
}

extern "C" void kernel_launch(void* const* d_in, const int* in_sizes, int n_in,
                              void* d_out, int out_size, void* d_ws, size_t ws_size,
                              hipStream_t stream) {
  const float* phi = (const float*)d_in[0];
  const float* W = (const float*)d_in[1];
  const float* b = (const float*)d_in[2];
  float* out = (float*)d_out;
  _Float16* wt2 = (_Float16*)d_ws;  // 64 shifts x 64x64 f16 = 512 KB

  wt2_prep<<<dim3(64), dim3(256), 0, stream>>>(W, wt2);
  equiv_main<<<dim3(2049), dim3(256), 0, stream>>>(phi, W, b, wt2, out);
}